// Round 12
// baseline (666.516 us; speedup 1.0000x reference)
//
#include <hip/hip_runtime.h>
#include <hip/hip_bf16.h>

typedef __attribute__((ext_vector_type(4))) float float4v;
typedef __attribute__((ext_vector_type(2))) float float2v;
typedef __attribute__((ext_vector_type(8))) short short8;
typedef __attribute__((ext_vector_type(4))) float f32x4;

#define NEGV (-1000000000.0f)

// B=64, L=2048, E=512, Q=256; M = 131072, K = 512, N = 512
#define MTOT (64 * 2048)

__device__ __forceinline__ unsigned short f2bf(float f) {
    unsigned int u = __float_as_uint(f);
    u += 0x7fffu + ((u >> 16) & 1u);   // RNE round to bf16
    return (unsigned short)(u >> 16);
}

__device__ __forceinline__ __hip_bfloat162 f22bf(float a, float b) {
    float2 f; f.x = a; f.y = b;
    return __float22bfloat162_rn(f);   // RNE pair convert (v_cvt_pk_bf16_f32)
}

// Wt[e][c] = bf16(W1[c][e]) via LDS 32x32 tile transpose (coalesced both sides).
__global__ __launch_bounds__(256)
void prep_wt_kernel(const float* __restrict__ W1, unsigned short* __restrict__ Wt) {
    __shared__ float t[32][33];
    int bx = blockIdx.x & 15;    // c tile
    int by = blockIdx.x >> 4;    // e tile
    int tx = threadIdx.x & 31;
    int ty = threadIdx.x >> 5;   // 0..7
    #pragma unroll
    for (int i = 0; i < 4; ++i)
        t[ty + 8 * i][tx] = W1[(bx * 32 + ty + 8 * i) * 512 + by * 32 + tx];
    __syncthreads();
    #pragma unroll
    for (int i = 0; i < 4; ++i)
        Wt[(by * 32 + ty + 8 * i) * 512 + bx * 32 + tx] = f2bf(t[tx][ty + 8 * i]);
}

// qc[b][e] = b1[e] + sum_q query[b][q] * W1[512+q][e]
__global__ void prep_qc_kernel(const float* __restrict__ query, const float* __restrict__ W1,
                               const float* __restrict__ b1, float* __restrict__ qc) {
    int b = blockIdx.x;
    int e = threadIdx.x;           // 256 threads -> cols e and e+256
    float acc0 = b1[e];
    float acc1 = b1[e + 256];
    const float* w = W1 + 512 * 512;
    #pragma unroll 8
    for (int q = 0; q < 256; ++q) {
        float qv = query[b * 256 + q];
        acc0 += qv * w[q * 512 + e];
        acc1 += qv * w[q * 512 + e + 256];
    }
    qc[b * 512 + e] = acc0;
    qc[b * 512 + e + 256] = acc1;
}

// Compact valid 128-row tiles into a worklist. meta[0]=count; meta[1]/meta[2]
// are the per-col-half ticket counters (all zeroed by hipMemsetAsync).
__global__ void build_wl_kernel(const int* __restrict__ length, int* __restrict__ wl,
                                int* __restrict__ meta) {
    int bm = blockIdx.x * 256 + threadIdx.x;   // 0..1023
    int b = bm >> 4;
    int l0 = (bm & 15) * 128;
    if (l0 < length[b]) {
        int idx = atomicAdd(&meta[0], 1);
        wl[idx] = bm;
    }
}

// B-in-registers GEMM: wave owns 16 cols x full K=512 (breg[16] = 64 VGPR,
// loaded once from L2-hot Wt). tanh is per-column, so col-partials combine
// linearly AFTER tanh -> no inter-wave communication. A streams global->reg
// via a 4-slot distance-3 ring (plain C loads; compiler emits counted vmcnt).
// ZERO __syncthreads in the pipeline; one naked s_barrier per 16-row panel
// keeps the 16 waves in lockstep so the shared 32KB A-panel stays L1-hot.
// 256 blocks (1/CU), block parity = col-half, dynamic tickets over valid
// 128-row tiles. Per-panel logit partials -> per-wave LDS, flushed per ticket.
__global__ __launch_bounds__(1024)
void gemm_logits_kernel(const float* __restrict__ A,            // encoded [M][512] f32
                        const unsigned short* __restrict__ Wt,  // [512 n][512 k] bf16
                        const float* __restrict__ qc,           // [64][512]
                        const float* __restrict__ v,            // [512]
                        const int* __restrict__ wl,             // valid bm list
                        int* __restrict__ meta,                 // [0]=n, [1],[2]=tickets
                        float* __restrict__ part)               // [32][M] partial logits
{
    __shared__ float lpart[16][128];
    __shared__ int s_t;

    int tid = threadIdx.x;
    int lane = tid & 63;
    int w = tid >> 6;              // 0..15
    int ch = blockIdx.x & 1;       // col half (B-residency never reloads)
    int c0 = ch * 256 + w * 16;    // wave's 16-col base
    int cg = ch * 16 + w;          // part slice 0..31
    int lc = lane & 15;
    int lg = lane >> 4;

    // B resident in VGPRs: breg[s] = cols c0..c0+15, k = s*32 + lg*8 .. +8
    short8 breg[16];
    {
        const unsigned short* Bb = Wt + (long)(c0 + lc) * 512 + lg * 8;
        #pragma unroll
        for (int s = 0; s < 16; ++s)
            breg[s] = *(const short8*)(Bb + s * 32);
    }
    float vv = v[c0 + lc];
    int nvalid = meta[0];
    int* tick = meta + 1 + ch;

    for (;;) {
        if (tid == 0) s_t = atomicAdd(tick, 1);
        __syncthreads();
        int t = s_t;
        if (t >= nvalid) break;
        int bm = wl[t];
        int b = bm >> 4;
        long row0 = (long)bm * 128;
        float qcol = qc[b * 512 + c0 + lc];

        // A fragment stream: lane covers row (panel row base + lc), 32B k-slice
        const char* gA = (const char*)(A + (row0 + lc) * 512 + lg * 8);
        float4v st[4][2];
        st[0][0] = *(const float4v*)(gA);       st[0][1] = *(const float4v*)(gA + 16);
        st[1][0] = *(const float4v*)(gA + 128); st[1][1] = *(const float4v*)(gA + 144);
        st[2][0] = *(const float4v*)(gA + 256); st[2][1] = *(const float4v*)(gA + 272);
        gA += 384;                 // points at flat step 3 (distance-3 ring)

        float* lp = &lpart[w][0];

        #pragma unroll 1
        for (int p = 0; p < 8; ++p) {          // 8 panels of 16 rows
            f32x4 acc = {};
            #pragma unroll
            for (int s = 0; s < 16; ++s) {     // K steps, fully unrolled
                if (p < 7 || s < 13) {         // stop issuing at flat step 127
                    st[(s + 3) & 3][0] = *(const float4v*)(gA);
                    st[(s + 3) & 3][1] = *(const float4v*)(gA + 16);
                    gA += (s == 12) ? 30848 : 128;   // panel-cross jump after (p,15)
                }
                union { __hip_bfloat162 h2[4]; short8 s8; } uf;
                uf.h2[0] = f22bf(st[s & 3][0][0], st[s & 3][0][1]);
                uf.h2[1] = f22bf(st[s & 3][0][2], st[s & 3][0][3]);
                uf.h2[2] = f22bf(st[s & 3][1][0], st[s & 3][1][1]);
                uf.h2[3] = f22bf(st[s & 3][1][2], st[s & 3][1][3]);
                acc = __builtin_amdgcn_mfma_f32_16x16x32_bf16(uf.s8, breg[s], acc, 0, 0, 0);
            }
            // panel epilogue: u = tanh(acc + qc), 16-col v-dot via shfl reduce
            #pragma unroll
            for (int j = 0; j < 4; ++j) {
                float x = acc[j] + qcol;
                float e2 = __expf(2.0f * x);
                float tt = 1.0f - 2.0f * __builtin_amdgcn_rcpf(e2 + 1.0f);
                float s2 = tt * vv;
                s2 += __shfl_xor(s2, 1);
                s2 += __shfl_xor(s2, 2);
                s2 += __shfl_xor(s2, 4);
                s2 += __shfl_xor(s2, 8);
                if (lc == 0) lp[p * 16 + lg * 4 + j] = s2;   // row = lg*4+j
            }
            __builtin_amdgcn_s_barrier();      // naked barrier: lockstep, loads stay in flight
        }
        // flush this wave's 128 logit-partials (own LDS region, no cross-wave dep)
        float2v o = *(const float2v*)(lp + lane * 2);
        *(float2v*)(part + (long)cg * MTOT + row0 + lane * 2) = o;
    }
}

// masked softmax per batch row; sums 32 col-group partials; zeroes ctx[b]
__global__ void softmax_kernel(const float* __restrict__ part, const int* __restrict__ length,
                               float* __restrict__ att, float* __restrict__ ctx) {
    int b = blockIdx.x;
    int len = length[b];
    int tid = threadIdx.x;     // 256
    int lane = tid & 63, wv = tid >> 6;
    const float* p0 = part + b * 2048;
    float* ab = att + b * 2048;

    ctx[b * 512 + tid] = 0.f;              // zero context (ctx_kernel atomicAdds)
    ctx[b * 512 + 256 + tid] = 0.f;

    float vals[8];
    float mymax = -3.402823466e38f;
    #pragma unroll
    for (int i = 0; i < 8; ++i) {
        int l = tid + i * 256;
        float xv = NEGV;
        if (l < len) {
            xv = 0.f;
            #pragma unroll
            for (int s = 0; s < 32; ++s)
                xv += p0[(long)s * MTOT + l];
        }
        vals[i] = xv;
        mymax = fmaxf(mymax, xv);
    }
    #pragma unroll
    for (int m = 32; m; m >>= 1) mymax = fmaxf(mymax, __shfl_xor(mymax, m));
    __shared__ float sm[4];
    if (lane == 0) sm[wv] = mymax;
    __syncthreads();
    float bmax = fmaxf(fmaxf(sm[0], sm[1]), fmaxf(sm[2], sm[3]));

    float mysum = 0.f;
    #pragma unroll
    for (int i = 0; i < 8; ++i) {
        int l = tid + i * 256;
        float e = (l < len) ? __expf(vals[i] - bmax) : 0.f;
        vals[i] = e;
        mysum += e;
    }
    #pragma unroll
    for (int m = 32; m; m >>= 1) mysum += __shfl_xor(mysum, m);
    __shared__ float ss[4];
    if (lane == 0) ss[wv] = mysum;
    __syncthreads();
    float tot = ss[0] + ss[1] + ss[2] + ss[3];
    float inv = 1.0f / (tot + 1e-5f);
    #pragma unroll
    for (int i = 0; i < 8; ++i) {
        int l = tid + i * 256;
        ab[l] = vals[i] * inv;
    }
}

// context[b][e] = sum_l att[b][l] * enc[b][l][e]; skip masked L-chunks
__global__ void ctx_kernel(const float* __restrict__ att, const float* __restrict__ enc,
                           const int* __restrict__ length, float* __restrict__ ctx) {
    int b = blockIdx.x;        // 64
    int lc = blockIdx.y;       // 16 chunks of 128
    int len = length[b];
    int l0 = lc * 128;
    if (l0 >= len) return;
    int lim = len - l0;
    if (lim > 128) lim = 128;

    int t = threadIdx.x;       // 256 -> 2 cols each
    const float* ab = att + b * 2048 + l0;
    const float* eb = enc + ((long)(b * 2048 + l0)) * 512 + t * 2;
    float c0 = 0.f, c1 = 0.f;
    #pragma unroll 4
    for (int l = 0; l < lim; ++l) {
        float a = ab[l];
        float2v e = *(const float2v*)(eb);
        eb += 512;
        c0 += a * e.x;
        c1 += a * e.y;
    }
    atomicAdd(&ctx[b * 512 + 2 * t], c0);
    atomicAdd(&ctx[b * 512 + 2 * t + 1], c1);
}

extern "C" void kernel_launch(void* const* d_in, const int* in_sizes, int n_in,
                              void* d_out, int out_size, void* d_ws, size_t ws_size,
                              hipStream_t stream) {
    const float* enc    = (const float*)d_in[0];   // [64,2048,512]
    const float* query  = (const float*)d_in[1];   // [64,256]
    const int*   length = (const int*)d_in[2];     // [64]
    const float* W1     = (const float*)d_in[3];   // [768,512]
    const float* b1     = (const float*)d_in[4];   // [512]
    const float* v      = (const float*)d_in[5];   // [512]

    float* out = (float*)d_out;
    float* ctx = out;                // [64,512]
    float* att = out + 64 * 512;     // [64,2048]

    char* ws = (char*)d_ws;
    float* part        = (float*)ws;                               // 32*M f32 = 16MB
    float* qc          = (float*)(ws + 32L * MTOT * 4);            // 128KB
    unsigned short* Wt = (unsigned short*)(ws + 32L * MTOT * 4 + 64 * 512 * 4); // 512KB
    int* wl            = (int*)(ws + 32L * MTOT * 4 + 64 * 512 * 4 + 512 * 1024); // 4KB
    int* meta          = (int*)(ws + 32L * MTOT * 4 + 64 * 512 * 4 + 512 * 1024 + 4096); // 12B

    hipMemsetAsync(meta, 0, 12, stream);
    prep_wt_kernel<<<256, 256, 0, stream>>>(W1, Wt);
    prep_qc_kernel<<<64, 256, 0, stream>>>(query, W1, b1, qc);
    build_wl_kernel<<<4, 256, 0, stream>>>(length, wl, meta);

    gemm_logits_kernel<<<256, 1024, 0, stream>>>(enc, Wt, qc, v, wl, meta, part);

    softmax_kernel<<<64, 256, 0, stream>>>(part, length, att, ctx);

    dim3 g3(64, 16);
    ctx_kernel<<<g3, 256, 0, stream>>>(att, enc, length, ctx);
}

// Round 13
// 155.560 us; speedup vs baseline: 4.2846x; 4.2846x over previous
//
#include <hip/hip_runtime.h>

typedef __attribute__((ext_vector_type(4))) float float4v;
typedef __attribute__((ext_vector_type(2))) float float2v;
typedef __attribute__((ext_vector_type(8))) short short8;
typedef __attribute__((ext_vector_type(4))) float f32x4;

#define NEGV (-1000000000.0f)

// B=64, L=2048, E=512, Q=256; M = 131072, K = 512, N = 512
#define MTOT (64 * 2048)

__device__ __forceinline__ unsigned short f2bf(float f) {
    unsigned int u = __float_as_uint(f);
    u += 0x7fffu + ((u >> 16) & 1u);   // RNE round to bf16
    return (unsigned short)(u >> 16);
}

// async global->LDS, 16B per lane, LDS dest = wave-uniform base + lane*16
__device__ __forceinline__ void gload_lds16(const void* g, void* l) {
    __builtin_amdgcn_global_load_lds(
        (__attribute__((address_space(1))) unsigned int*)(unsigned long long)(g),
        (__attribute__((address_space(3))) unsigned int*)(unsigned int)(unsigned long long)(l),
        16, 0, 0);
}

// Wt[e][c] = bf16(W1[c][e]) via LDS 32x32 tile transpose.
__global__ __launch_bounds__(256)
void prep_wt_kernel(const float* __restrict__ W1, unsigned short* __restrict__ Wt) {
    __shared__ float t[32][33];
    int bx = blockIdx.x & 15;    // c tile
    int by = blockIdx.x >> 4;    // e tile
    int tx = threadIdx.x & 31;
    int ty = threadIdx.x >> 5;   // 0..7
    #pragma unroll
    for (int i = 0; i < 4; ++i)
        t[ty + 8 * i][tx] = W1[(bx * 32 + ty + 8 * i) * 512 + by * 32 + tx];
    __syncthreads();
    #pragma unroll
    for (int i = 0; i < 4; ++i)
        Wt[(by * 32 + ty + 8 * i) * 512 + bx * 32 + tx] = f2bf(t[tx][ty + 8 * i]);
}

// qc[b][e] = b1[e] + sum_q query[b][q] * W1[512+q][e]
__global__ void prep_qc_kernel(const float* __restrict__ query, const float* __restrict__ W1,
                               const float* __restrict__ b1, float* __restrict__ qc) {
    int b = blockIdx.x;
    int e = threadIdx.x;           // 256 threads -> cols e and e+256
    float acc0 = b1[e];
    float acc1 = b1[e + 256];
    const float* w = W1 + 512 * 512;
    #pragma unroll 8
    for (int q = 0; q < 256; ++q) {
        float qv = query[b * 256 + q];
        acc0 += qv * w[q * 512 + e];
        acc1 += qv * w[q * 512 + e + 256];
    }
    qc[b * 512 + e] = acc0;
    qc[b * 512 + e + 256] = acc1;
}

// Ab = bf16(enc) for valid 128-row tiles only (skipped tiles never read).
__global__ __launch_bounds__(256)
void prep_enc_kernel(const float* __restrict__ enc, const int* __restrict__ length,
                     unsigned short* __restrict__ Ab) {
    int bm = blockIdx.x;           // 0..1023
    int b = bm >> 4;
    if ((bm & 15) * 128 >= length[b]) return;
    long base = (long)bm * 128 * 512;
    const float* src = enc + base;
    unsigned short* dst = Ab + base;
    int tid = threadIdx.x;
    #pragma unroll 4
    for (int i = 0; i < 32; ++i) {
        long idx = (long)(i * 256 + tid) * 8;
        float4v a = *(const float4v*)(src + idx);
        float4v c = *(const float4v*)(src + idx + 4);
        union { unsigned short u[8]; short8 s; } o;
        o.u[0] = f2bf(a[0]); o.u[1] = f2bf(a[1]); o.u[2] = f2bf(a[2]); o.u[3] = f2bf(a[3]);
        o.u[4] = f2bf(c[0]); o.u[5] = f2bf(c[1]); o.u[6] = f2bf(c[2]); o.u[7] = f2bf(c[3]);
        *(short8*)(dst + idx) = o.s;
    }
}

// Compact valid 128-row tiles into a worklist. meta[0]=count, meta[1]=ticket.
__global__ void build_wl_kernel(const int* __restrict__ length, int* __restrict__ wl,
                                int* __restrict__ meta) {
    int bm = blockIdx.x * 256 + threadIdx.x;   // 0..1023
    int b = bm >> 4;
    if ((bm & 15) * 128 < length[b]) {
        int idx = atomicAdd(&meta[0], 1);
        wl[idx] = bm;
    }
}

// Pure-bf16 GEMM, 128x256 tile, BK=64, 8 waves, 3-slot LDS ring (144KB),
// counted vmcnt(12) — loads stay in flight across ALL barriers, zero in-loop
// drains (T3+T4). A and B both staged via global_load_lds with pre-swizzled
// sources (byte ^= (row&7)<<4 within 128B rows -> 2 lanes/bank, conflict-free).
// Persistent blocks + ticket queue (R11 infra). R4's 8-slice epilogue.
__global__ __launch_bounds__(512)
void gemm_logits_kernel(const unsigned short* __restrict__ Ab,  // [M][512] bf16
                        const unsigned short* __restrict__ Wt,  // [512 n][512 k] bf16
                        const float* __restrict__ qc,           // [64][512]
                        const float* __restrict__ v,            // [512]
                        const int* __restrict__ wl,             // valid bm list
                        int* __restrict__ meta,                 // [0]=n, [1]=ticket
                        float* __restrict__ part)               // [8][M] partials
{
    __shared__ unsigned short As[3 * 128 * 64];  // 3 x 16 KB
    __shared__ unsigned short Bs[3 * 256 * 64];  // 3 x 32 KB
    __shared__ int s_t;

    int tid = threadIdx.x;
    int lane = tid & 63;
    int w = tid >> 6;              // 0..7
    int wm = w >> 2, wn = w & 3;   // 2 x 4 wave grid; wave tile 64x64

    // staging geometry (tile-independent): linear LDS offsets per wave
    int aoffs[2], boffs[4];        // linear slot offsets
    int asrc[2], bsrc[4];          // pre-swizzled source byte offsets (k-step 0)
    #pragma unroll
    for (int i = 0; i < 2; ++i) {
        int off = (w * 2 + i) * 1024 + lane * 16;
        int r = off >> 7, kb = off & 127;
        aoffs[i] = off;
        asrc[i] = r * 1024 + (kb ^ ((r & 7) << 4));
    }
    #pragma unroll
    for (int i = 0; i < 4; ++i) {
        int off = (w * 4 + i) * 1024 + lane * 16;
        int r = off >> 7, kb = off & 127;
        boffs[i] = off;
        bsrc[i] = r * 1024 + (kb ^ ((r & 7) << 4));
    }

    // fragment read byte offsets (within a slot), kk = K-half of BK=64
    int aoff[4][2], boff[4][2];
    int kbase = (lane >> 4) * 16;
    #pragma unroll
    for (int mi = 0; mi < 4; ++mi) {
        int ar = wm * 64 + (lane & 15) + mi * 16;
        #pragma unroll
        for (int kk = 0; kk < 2; ++kk)
            aoff[mi][kk] = ar * 128 + ((kk * 64 + kbase) ^ ((ar & 7) << 4));
    }
    #pragma unroll
    for (int ni = 0; ni < 4; ++ni) {
        int br = wn * 64 + (lane & 15) + ni * 16;
        #pragma unroll
        for (int kk = 0; kk < 2; ++kk)
            boff[ni][kk] = br * 128 + ((kk * 64 + kbase) ^ ((br & 7) << 4));
    }

    int nw = meta[0] * 2;          // 2 bn tickets per valid bm

    for (;;) {
        if (tid == 0) s_t = atomicAdd(&meta[1], 1);
        __syncthreads();           // broadcast + protect LDS reuse across tickets
        int t = s_t;
        if (t >= nw) break;
        int bm = wl[t >> 1];
        int bn = t & 1;
        int b = bm >> 4;
        long row0 = (long)bm * 128;
        int col0 = bn * 256;

        const char* gA = (const char*)Ab + row0 * 1024;
        const char* gB = (const char*)Wt + (long)col0 * 1024;

        f32x4 acc[4][4] = {};

#define STAGE(t_, sI) do {                                                   \
    char* la_ = (char*)As + (sI) * 16384;                                    \
    char* lb_ = (char*)Bs + (sI) * 32768;                                    \
    gload_lds16(gA + asrc[0] + (t_) * 128, la_ + aoffs[0]);                  \
    gload_lds16(gA + asrc[1] + (t_) * 128, la_ + aoffs[1]);                  \
    gload_lds16(gB + bsrc[0] + (t_) * 128, lb_ + boffs[0]);                  \
    gload_lds16(gB + bsrc[1] + (t_) * 128, lb_ + boffs[1]);                  \
    gload_lds16(gB + bsrc[2] + (t_) * 128, lb_ + boffs[2]);                  \
    gload_lds16(gB + bsrc[3] + (t_) * 128, lb_ + boffs[3]);                  \
} while (0)

#define KCOMP(sC) do {                                                       \
    const char* as_ = (const char*)As + (sC) * 16384;                        \
    const char* bs_ = (const char*)Bs + (sC) * 32768;                        \
    _Pragma("unroll")                                                        \
    for (int kk = 0; kk < 2; ++kk) {                                         \
        short8 af_[4];                                                       \
        _Pragma("unroll")                                                    \
        for (int mi = 0; mi < 4; ++mi)                                       \
            af_[mi] = *(const short8*)(as_ + aoff[mi][kk]);                  \
        _Pragma("unroll")                                                    \
        for (int ni = 0; ni < 4; ++ni) {                                     \
            short8 bf_ = *(const short8*)(bs_ + boff[ni][kk]);               \
            _Pragma("unroll")                                                \
            for (int mi = 0; mi < 4; ++mi)                                   \
                acc[mi][ni] = __builtin_amdgcn_mfma_f32_16x16x32_bf16(af_[mi], bf_, acc[mi][ni], 0, 0, 0); \
        }                                                                    \
    }                                                                        \
} while (0)

#define KITER(t_, stg_, sI_, sC_, VM_) do {                                  \
    STAGE(stg_, sI_);                                                        \
    asm volatile("s_waitcnt vmcnt(" #VM_ ")" ::: "memory");                  \
    __builtin_amdgcn_s_barrier();                                            \
    asm volatile("" ::: "memory");                                           \
    KCOMP(sC_);                                                              \
    asm volatile("" ::: "memory");                                           \
    __builtin_amdgcn_s_barrier();                                            \
} while (0)

        STAGE(0, 0);
        STAGE(1, 1);
        KITER(0, 2, 2, 0, 12);
        KITER(1, 3, 0, 1, 12);
        KITER(2, 4, 1, 2, 12);
        KITER(3, 5, 2, 0, 12);
        KITER(4, 6, 0, 1, 12);
        KITER(5, 7, 1, 2, 12);
        // t = 6: no stage left
        asm volatile("s_waitcnt vmcnt(6)" ::: "memory");
        __builtin_amdgcn_s_barrier();
        asm volatile("" ::: "memory");
        KCOMP(0);
        asm volatile("" ::: "memory");
        __builtin_amdgcn_s_barrier();
        // t = 7
        asm volatile("s_waitcnt vmcnt(0)" ::: "memory");
        __builtin_amdgcn_s_barrier();
        asm volatile("" ::: "memory");
        KCOMP(1);

        // epilogue: u = tanh(acc + qc), 64-col partial via 16-lane reduce,
        // store into slice (bn*4 + wn) — unique writer per (slice,row).
        const float* qcb = qc + b * 512;
        float vcol[4], qcol[4];
        #pragma unroll
        for (int ni = 0; ni < 4; ++ni) {
            int c = col0 + wn * 64 + ni * 16 + (lane & 15);
            vcol[ni] = v[c];
            qcol[ni] = qcb[c];
        }
        float* pslice = part + (bn * 4 + wn) * MTOT + row0;
        int rbase = wm * 64 + 4 * (lane >> 4);
        #pragma unroll
        for (int mi = 0; mi < 4; ++mi) {
            #pragma unroll
            for (int j2 = 0; j2 < 4; ++j2) {
                float s = 0.f;
                #pragma unroll
                for (int ni = 0; ni < 4; ++ni) {
                    float xx = acc[mi][ni][j2] + qcol[ni];
                    float e2 = __expf(2.0f * xx);
                    float tt = 1.0f - 2.0f * __builtin_amdgcn_rcpf(e2 + 1.0f);
                    s += tt * vcol[ni];
                }
                s += __shfl_xor(s, 1);
                s += __shfl_xor(s, 2);
                s += __shfl_xor(s, 4);
                s += __shfl_xor(s, 8);
                if ((lane & 15) == 0)
                    pslice[rbase + mi * 16 + j2] = s;
            }
        }
    }
}

// masked softmax per batch row; sums 8 slices; zeroes ctx[b]
__global__ void softmax_kernel(const float* __restrict__ part, const int* __restrict__ length,
                               float* __restrict__ att, float* __restrict__ ctx) {
    int b = blockIdx.x;
    int len = length[b];
    int tid = threadIdx.x;     // 256
    int lane = tid & 63, wv = tid >> 6;
    const float* p0 = part + b * 2048;
    float* ab = att + b * 2048;

    ctx[b * 512 + tid] = 0.f;
    ctx[b * 512 + 256 + tid] = 0.f;

    float vals[8];
    float mymax = -3.402823466e38f;
    #pragma unroll
    for (int i = 0; i < 8; ++i) {
        int l = tid + i * 256;
        float xv = NEGV;
        if (l < len) {
            xv = 0.f;
            #pragma unroll
            for (int s = 0; s < 8; ++s)
                xv += p0[s * MTOT + l];
        }
        vals[i] = xv;
        mymax = fmaxf(mymax, xv);
    }
    #pragma unroll
    for (int m = 32; m; m >>= 1) mymax = fmaxf(mymax, __shfl_xor(mymax, m));
    __shared__ float sm[4];
    if (lane == 0) sm[wv] = mymax;
    __syncthreads();
    float bmax = fmaxf(fmaxf(sm[0], sm[1]), fmaxf(sm[2], sm[3]));

    float mysum = 0.f;
    #pragma unroll
    for (int i = 0; i < 8; ++i) {
        int l = tid + i * 256;
        float e = (l < len) ? __expf(vals[i] - bmax) : 0.f;
        vals[i] = e;
        mysum += e;
    }
    #pragma unroll
    for (int m = 32; m; m >>= 1) mysum += __shfl_xor(mysum, m);
    __shared__ float ss[4];
    if (lane == 0) ss[wv] = mysum;
    __syncthreads();
    float tot = ss[0] + ss[1] + ss[2] + ss[3];
    float inv = 1.0f / (tot + 1e-5f);
    #pragma unroll
    for (int i = 0; i < 8; ++i) {
        int l = tid + i * 256;
        ab[l] = vals[i] * inv;
    }
}

// context[b][e] = sum_l att[b][l] * Ab[b][l][e] (bf16 enc copy; half the bytes)
__global__ void ctx_kernel(const float* __restrict__ att, const unsigned short* __restrict__ Ab,
                           const int* __restrict__ length, float* __restrict__ ctx) {
    int b = blockIdx.x;        // 64
    int lc = blockIdx.y;       // 16 chunks of 128
    int len = length[b];
    int l0 = lc * 128;
    if (l0 >= len) return;
    int lim = len - l0;
    if (lim > 128) lim = 128;

    int t = threadIdx.x;       // 256 -> 2 cols each
    const float* ab = att + b * 2048 + l0;
    const unsigned short* eb = Ab + ((long)(b * 2048 + l0)) * 512 + t * 2;
    float c0 = 0.f, c1 = 0.f;
    #pragma unroll 4
    for (int l = 0; l < lim; ++l) {
        float a = ab[l];
        unsigned int wv = *(const unsigned int*)(eb);
        eb += 512;
        c0 += a * __uint_as_float(wv << 16);
        c1 += a * __uint_as_float(wv & 0xffff0000u);
    }
    atomicAdd(&ctx[b * 512 + 2 * t], c0);
    atomicAdd(&ctx[b * 512 + 2 * t + 1], c1);
}

extern "C" void kernel_launch(void* const* d_in, const int* in_sizes, int n_in,
                              void* d_out, int out_size, void* d_ws, size_t ws_size,
                              hipStream_t stream) {
    const float* enc    = (const float*)d_in[0];   // [64,2048,512]
    const float* query  = (const float*)d_in[1];   // [64,256]
    const int*   length = (const int*)d_in[2];     // [64]
    const float* W1     = (const float*)d_in[3];   // [768,512]
    const float* b1     = (const float*)d_in[4];   // [512]
    const float* v      = (const float*)d_in[5];   // [512]

    float* out = (float*)d_out;
    float* ctx = out;                // [64,512]
    float* att = out + 64 * 512;     // [64,2048]

    char* ws = (char*)d_ws;
    float* part        = (float*)ws;                               // 8*M f32 = 4MB
    float* qc          = (float*)(ws + 8L * MTOT * 4);             // 128KB
    unsigned short* Wt = (unsigned short*)(ws + 8L * MTOT * 4 + 64 * 512 * 4); // 512KB
    int* wl            = (int*)(ws + 8L * MTOT * 4 + 64 * 512 * 4 + 512 * 1024); // 4KB
    int* meta          = (int*)(ws + 8L * MTOT * 4 + 64 * 512 * 4 + 512 * 1024 + 4096); // 8B
    unsigned short* Ab = (unsigned short*)(ws + 8L * MTOT * 4 + 64 * 512 * 4 + 512 * 1024 + 8192); // 128MB

    hipMemsetAsync(meta, 0, 8, stream);
    prep_wt_kernel<<<256, 256, 0, stream>>>(W1, Wt);
    prep_qc_kernel<<<64, 256, 0, stream>>>(query, W1, b1, qc);
    build_wl_kernel<<<4, 256, 0, stream>>>(length, wl, meta);
    prep_enc_kernel<<<1024, 256, 0, stream>>>(enc, length, Ab);

    gemm_logits_kernel<<<256, 512, 0, stream>>>(Ab, Wt, qc, v, wl, meta, part);

    softmax_kernel<<<64, 256, 0, stream>>>(part, length, att, ctx);

    dim3 g3(64, 16);
    ctx_kernel<<<g3, 256, 0, stream>>>(att, Ab, length, ctx);
}

// Round 14
// 155.493 us; speedup vs baseline: 4.2865x; 1.0004x over previous
//
#include <hip/hip_runtime.h>

typedef __attribute__((ext_vector_type(4))) float float4v;
typedef __attribute__((ext_vector_type(2))) float float2v;
typedef __attribute__((ext_vector_type(8))) short short8;
typedef __attribute__((ext_vector_type(4))) float f32x4;

#define NEGV (-1000000000.0f)

// B=64, L=2048, E=512, Q=256; M = 131072, K = 512, N = 512
#define MTOT (64 * 2048)

__device__ __forceinline__ unsigned short f2bf(float f) {
    unsigned int u = __float_as_uint(f);
    u += 0x7fffu + ((u >> 16) & 1u);   // RNE round to bf16
    return (unsigned short)(u >> 16);
}

// async global->LDS, 16B per lane, LDS dest = wave-uniform base + lane*16
__device__ __forceinline__ void gload_lds16(const void* g, void* l) {
    __builtin_amdgcn_global_load_lds(
        (__attribute__((address_space(1))) unsigned int*)(unsigned long long)(g),
        (__attribute__((address_space(3))) unsigned int*)(unsigned int)(unsigned long long)(l),
        16, 0, 0);
}

// Wt[e][c] = bf16(W1[c][e]) via LDS 32x32 tile transpose.
__global__ __launch_bounds__(256)
void prep_wt_kernel(const float* __restrict__ W1, unsigned short* __restrict__ Wt) {
    __shared__ float t[32][33];
    int bx = blockIdx.x & 15;    // c tile
    int by = blockIdx.x >> 4;    // e tile
    int tx = threadIdx.x & 31;
    int ty = threadIdx.x >> 5;   // 0..7
    #pragma unroll
    for (int i = 0; i < 4; ++i)
        t[ty + 8 * i][tx] = W1[(bx * 32 + ty + 8 * i) * 512 + by * 32 + tx];
    __syncthreads();
    #pragma unroll
    for (int i = 0; i < 4; ++i)
        Wt[(by * 32 + ty + 8 * i) * 512 + bx * 32 + tx] = f2bf(t[tx][ty + 8 * i]);
}

// qc[b][e] = b1[e] + sum_q query[b][q] * W1[512+q][e]
__global__ void prep_qc_kernel(const float* __restrict__ query, const float* __restrict__ W1,
                               const float* __restrict__ b1, float* __restrict__ qc) {
    int b = blockIdx.x;
    int e = threadIdx.x;           // 256 threads -> cols e and e+256
    float acc0 = b1[e];
    float acc1 = b1[e + 256];
    const float* w = W1 + 512 * 512;
    #pragma unroll 8
    for (int q = 0; q < 256; ++q) {
        float qv = query[b * 256 + q];
        acc0 += qv * w[q * 512 + e];
        acc1 += qv * w[q * 512 + e + 256];
    }
    qc[b * 512 + e] = acc0;
    qc[b * 512 + e + 256] = acc1;
}

// Ab = bf16(enc) for valid 128-row tiles only (skipped tiles never read).
__global__ __launch_bounds__(256)
void prep_enc_kernel(const float* __restrict__ enc, const int* __restrict__ length,
                     unsigned short* __restrict__ Ab) {
    int bm = blockIdx.x;           // 0..1023
    int b = bm >> 4;
    if ((bm & 15) * 128 >= length[b]) return;
    long base = (long)bm * 128 * 512;
    const float* src = enc + base;
    unsigned short* dst = Ab + base;
    int tid = threadIdx.x;
    #pragma unroll 4
    for (int i = 0; i < 32; ++i) {
        long idx = (long)(i * 256 + tid) * 8;
        float4v a = *(const float4v*)(src + idx);
        float4v c = *(const float4v*)(src + idx + 4);
        union { unsigned short u[8]; short8 s; } o;
        o.u[0] = f2bf(a[0]); o.u[1] = f2bf(a[1]); o.u[2] = f2bf(a[2]); o.u[3] = f2bf(a[3]);
        o.u[4] = f2bf(c[0]); o.u[5] = f2bf(c[1]); o.u[6] = f2bf(c[2]); o.u[7] = f2bf(c[3]);
        *(short8*)(dst + idx) = o.s;
    }
}

// Compact valid 128-row tiles into a worklist. meta[0]=count, meta[1]=ticket.
__global__ void build_wl_kernel(const int* __restrict__ length, int* __restrict__ wl,
                                int* __restrict__ meta) {
    int bm = blockIdx.x * 256 + threadIdx.x;   // 0..1023
    int b = bm >> 4;
    if ((bm & 15) * 128 < length[b]) {
        int idx = atomicAdd(&meta[0], 1);
        wl[idx] = bm;
    }
}

// Pure-bf16 GEMM, 128x256 tile, BK=64, 8 waves, 3-slot LDS ring (144KB),
// counted vmcnt — never drained in-loop (T4). R14: m201-style phase
// discipline inside each K-step: {issue 4 loads; vmcnt(10); barrier;
// setprio1; MFMA kk0; setprio0; issue 2 loads; setprio1; MFMA kk1;
// setprio0; barrier} — stage-issue and ds_read interleave with MFMA,
// setprio arbitrates the wave role-split (T5). Ticket prefetch hides the
// atomic under the epilogue.
__global__ __launch_bounds__(512)
void gemm_logits_kernel(const unsigned short* __restrict__ Ab,  // [M][512] bf16
                        const unsigned short* __restrict__ Wt,  // [512 n][512 k] bf16
                        const float* __restrict__ qc,           // [64][512]
                        const float* __restrict__ v,            // [512]
                        const int* __restrict__ wl,             // valid bm list
                        int* __restrict__ meta,                 // [0]=n, [1]=ticket
                        float* __restrict__ part)               // [8][M] partials
{
    __shared__ unsigned short As[3 * 128 * 64];  // 3 x 16 KB
    __shared__ unsigned short Bs[3 * 256 * 64];  // 3 x 32 KB
    __shared__ int s_t;

    int tid = threadIdx.x;
    int lane = tid & 63;
    int w = tid >> 6;              // 0..7
    int wm = w >> 2, wn = w & 3;   // 2 x 4 wave grid; wave tile 64x64

    // staging geometry (tile-independent): linear LDS offsets per wave
    int aoffs[2], boffs[4];        // linear slot offsets
    int asrc[2], bsrc[4];          // pre-swizzled source byte offsets (k-step 0)
    #pragma unroll
    for (int i = 0; i < 2; ++i) {
        int off = (w * 2 + i) * 1024 + lane * 16;
        int r = off >> 7, kb = off & 127;
        aoffs[i] = off;
        asrc[i] = r * 1024 + (kb ^ ((r & 7) << 4));
    }
    #pragma unroll
    for (int i = 0; i < 4; ++i) {
        int off = (w * 4 + i) * 1024 + lane * 16;
        int r = off >> 7, kb = off & 127;
        boffs[i] = off;
        bsrc[i] = r * 1024 + (kb ^ ((r & 7) << 4));
    }

    // fragment read byte offsets (within a slot), kk = K-half of BK=64
    int aoff[4][2], boff[4][2];
    int kbase = (lane >> 4) * 16;
    #pragma unroll
    for (int mi = 0; mi < 4; ++mi) {
        int ar = wm * 64 + (lane & 15) + mi * 16;
        #pragma unroll
        for (int kk = 0; kk < 2; ++kk)
            aoff[mi][kk] = ar * 128 + ((kk * 64 + kbase) ^ ((ar & 7) << 4));
    }
    #pragma unroll
    for (int ni = 0; ni < 4; ++ni) {
        int br = wn * 64 + (lane & 15) + ni * 16;
        #pragma unroll
        for (int kk = 0; kk < 2; ++kk)
            boff[ni][kk] = br * 128 + ((kk * 64 + kbase) ^ ((br & 7) << 4));
    }

    int nw = meta[0] * 2;          // 2 bn tickets per valid bm

    if (tid == 0) s_t = atomicAdd(&meta[1], 1);
    __syncthreads();
    int t = s_t;

    while (t < nw) {
        int bm = wl[t >> 1];
        int bn = t & 1;
        int b = bm >> 4;
        long row0 = (long)bm * 128;
        int col0 = bn * 256;

        const char* gA = (const char*)Ab + row0 * 1024;
        const char* gB = (const char*)Wt + (long)col0 * 1024;

        f32x4 acc[4][4] = {};

// first 4 issues (A x2 + B x2), then remaining 2 B issues
#define STAGE_A(t_, sI) do {                                                 \
    char* la_ = (char*)As + (sI) * 16384;                                    \
    char* lb_ = (char*)Bs + (sI) * 32768;                                    \
    gload_lds16(gA + asrc[0] + (t_) * 128, la_ + aoffs[0]);                  \
    gload_lds16(gA + asrc[1] + (t_) * 128, la_ + aoffs[1]);                  \
    gload_lds16(gB + bsrc[0] + (t_) * 128, lb_ + boffs[0]);                  \
    gload_lds16(gB + bsrc[1] + (t_) * 128, lb_ + boffs[1]);                  \
} while (0)

#define STAGE_B(t_, sI) do {                                                 \
    char* lb_ = (char*)Bs + (sI) * 32768;                                    \
    gload_lds16(gB + bsrc[2] + (t_) * 128, lb_ + boffs[2]);                  \
    gload_lds16(gB + bsrc[3] + (t_) * 128, lb_ + boffs[3]);                  \
} while (0)

#define KCOMP_K(sC, kk) do {                                                 \
    const char* as_ = (const char*)As + (sC) * 16384;                        \
    const char* bs_ = (const char*)Bs + (sC) * 32768;                        \
    short8 af_[4];                                                           \
    _Pragma("unroll")                                                        \
    for (int mi = 0; mi < 4; ++mi)                                           \
        af_[mi] = *(const short8*)(as_ + aoff[mi][kk]);                      \
    _Pragma("unroll")                                                        \
    for (int ni = 0; ni < 4; ++ni) {                                         \
        short8 bf_ = *(const short8*)(bs_ + boff[ni][kk]);                   \
        _Pragma("unroll")                                                    \
        for (int mi = 0; mi < 4; ++mi)                                       \
            acc[mi][ni] = __builtin_amdgcn_mfma_f32_16x16x32_bf16(af_[mi], bf_, acc[mi][ni], 0, 0, 0); \
    }                                                                        \
} while (0)

#define KITER(t_, stg_, sI_, sC_) do {                                       \
    STAGE_A(stg_, sI_);                                                      \
    asm volatile("s_waitcnt vmcnt(10)" ::: "memory");                        \
    __builtin_amdgcn_s_barrier();                                            \
    asm volatile("" ::: "memory");                                           \
    __builtin_amdgcn_s_setprio(1);                                           \
    KCOMP_K(sC_, 0);                                                         \
    __builtin_amdgcn_s_setprio(0);                                           \
    STAGE_B(stg_, sI_);                                                      \
    __builtin_amdgcn_s_setprio(1);                                           \
    KCOMP_K(sC_, 1);                                                         \
    __builtin_amdgcn_s_setprio(0);                                           \
    asm volatile("" ::: "memory");                                           \
    __builtin_amdgcn_s_barrier();                                            \
} while (0)

        STAGE_A(0, 0); STAGE_B(0, 0);
        STAGE_A(1, 1); STAGE_B(1, 1);
        KITER(0, 2, 2, 0);
        KITER(1, 3, 0, 1);
        KITER(2, 4, 1, 2);
        KITER(3, 5, 2, 0);
        KITER(4, 6, 0, 1);
        KITER(5, 7, 1, 2);
        // t = 6: no staging left
        asm volatile("s_waitcnt vmcnt(6)" ::: "memory");
        __builtin_amdgcn_s_barrier();
        asm volatile("" ::: "memory");
        __builtin_amdgcn_s_setprio(1);
        KCOMP_K(0, 0);
        KCOMP_K(0, 1);
        __builtin_amdgcn_s_setprio(0);
        asm volatile("" ::: "memory");
        __builtin_amdgcn_s_barrier();
        // t = 7
        asm volatile("s_waitcnt vmcnt(0)" ::: "memory");
        __builtin_amdgcn_s_barrier();
        asm volatile("" ::: "memory");
        KCOMP_K(1, 0);
        KCOMP_K(1, 1);

        // prefetch next ticket; atomic latency hides under the epilogue
        if (tid == 0) s_t = atomicAdd(&meta[1], 1);

        // epilogue: u = tanh(acc + qc), 64-col partial via 16-lane reduce,
        // store into slice (bn*4 + wn) — unique writer per (slice,row).
        const float* qcb = qc + b * 512;
        float vcol[4], qcol[4];
        #pragma unroll
        for (int ni = 0; ni < 4; ++ni) {
            int c = col0 + wn * 64 + ni * 16 + (lane & 15);
            vcol[ni] = v[c];
            qcol[ni] = qcb[c];
        }
        float* pslice = part + (bn * 4 + wn) * MTOT + row0;
        int rbase = wm * 64 + 4 * (lane >> 4);
        #pragma unroll
        for (int mi = 0; mi < 4; ++mi) {
            #pragma unroll
            for (int j2 = 0; j2 < 4; ++j2) {
                float s = 0.f;
                #pragma unroll
                for (int ni = 0; ni < 4; ++ni) {
                    float xx = acc[mi][ni][j2] + qcol[ni];
                    float e2 = __expf(2.0f * xx);
                    float tt = 1.0f - 2.0f * __builtin_amdgcn_rcpf(e2 + 1.0f);
                    s += tt * vcol[ni];
                }
                s += __shfl_xor(s, 1);
                s += __shfl_xor(s, 2);
                s += __shfl_xor(s, 4);
                s += __shfl_xor(s, 8);
                if ((lane & 15) == 0)
                    pslice[rbase + mi * 16 + j2] = s;
            }
        }
        __syncthreads();           // all waves see s_t; LDS safe for next ticket
        t = s_t;
    }
}

// masked softmax per batch row; sums 8 slices; zeroes ctx[b]
__global__ void softmax_kernel(const float* __restrict__ part, const int* __restrict__ length,
                               float* __restrict__ att, float* __restrict__ ctx) {
    int b = blockIdx.x;
    int len = length[b];
    int tid = threadIdx.x;     // 256
    int lane = tid & 63, wv = tid >> 6;
    const float* p0 = part + b * 2048;
    float* ab = att + b * 2048;

    ctx[b * 512 + tid] = 0.f;
    ctx[b * 512 + 256 + tid] = 0.f;

    float vals[8];
    float mymax = -3.402823466e38f;
    #pragma unroll
    for (int i = 0; i < 8; ++i) {
        int l = tid + i * 256;
        float xv = NEGV;
        if (l < len) {
            xv = 0.f;
            #pragma unroll
            for (int s = 0; s < 8; ++s)
                xv += p0[s * MTOT + l];
        }
        vals[i] = xv;
        mymax = fmaxf(mymax, xv);
    }
    #pragma unroll
    for (int m = 32; m; m >>= 1) mymax = fmaxf(mymax, __shfl_xor(mymax, m));
    __shared__ float sm[4];
    if (lane == 0) sm[wv] = mymax;
    __syncthreads();
    float bmax = fmaxf(fmaxf(sm[0], sm[1]), fmaxf(sm[2], sm[3]));

    float mysum = 0.f;
    #pragma unroll
    for (int i = 0; i < 8; ++i) {
        int l = tid + i * 256;
        float e = (l < len) ? __expf(vals[i] - bmax) : 0.f;
        vals[i] = e;
        mysum += e;
    }
    #pragma unroll
    for (int m = 32; m; m >>= 1) mysum += __shfl_xor(mysum, m);
    __shared__ float ss[4];
    if (lane == 0) ss[wv] = mysum;
    __syncthreads();
    float tot = ss[0] + ss[1] + ss[2] + ss[3];
    float inv = 1.0f / (tot + 1e-5f);
    #pragma unroll
    for (int i = 0; i < 8; ++i) {
        int l = tid + i * 256;
        ab[l] = vals[i] * inv;
    }
}

// context[b][e] = sum_l att[b][l] * Ab[b][l][e] (bf16 enc copy; half the bytes)
__global__ void ctx_kernel(const float* __restrict__ att, const unsigned short* __restrict__ Ab,
                           const int* __restrict__ length, float* __restrict__ ctx) {
    int b = blockIdx.x;        // 64
    int lc = blockIdx.y;       // 16 chunks of 128
    int len = length[b];
    int l0 = lc * 128;
    if (l0 >= len) return;
    int lim = len - l0;
    if (lim > 128) lim = 128;

    int t = threadIdx.x;       // 256 -> 2 cols each
    const float* ab = att + b * 2048 + l0;
    const unsigned short* eb = Ab + ((long)(b * 2048 + l0)) * 512 + t * 2;
    float c0 = 0.f, c1 = 0.f;
    #pragma unroll 4
    for (int l = 0; l < lim; ++l) {
        float a = ab[l];
        unsigned int wv = *(const unsigned int*)(eb);
        eb += 512;
        c0 += a * __uint_as_float(wv << 16);
        c1 += a * __uint_as_float(wv & 0xffff0000u);
    }
    atomicAdd(&ctx[b * 512 + 2 * t], c0);
    atomicAdd(&ctx[b * 512 + 2 * t + 1], c1);
}

extern "C" void kernel_launch(void* const* d_in, const int* in_sizes, int n_in,
                              void* d_out, int out_size, void* d_ws, size_t ws_size,
                              hipStream_t stream) {
    const float* enc    = (const float*)d_in[0];   // [64,2048,512]
    const float* query  = (const float*)d_in[1];   // [64,256]
    const int*   length = (const int*)d_in[2];     // [64]
    const float* W1     = (const float*)d_in[3];   // [768,512]
    const float* b1     = (const float*)d_in[4];   // [512]
    const float* v      = (const float*)d_in[5];   // [512]

    float* out = (float*)d_out;
    float* ctx = out;                // [64,512]
    float* att = out + 64 * 512;     // [64,2048]

    char* ws = (char*)d_ws;
    float* part        = (float*)ws;                               // 8*M f32 = 4MB
    float* qc          = (float*)(ws + 8L * MTOT * 4);             // 128KB
    unsigned short* Wt = (unsigned short*)(ws + 8L * MTOT * 4 + 64 * 512 * 4); // 512KB
    int* wl            = (int*)(ws + 8L * MTOT * 4 + 64 * 512 * 4 + 512 * 1024); // 4KB
    int* meta          = (int*)(ws + 8L * MTOT * 4 + 64 * 512 * 4 + 512 * 1024 + 4096); // 8B
    unsigned short* Ab = (unsigned short*)(ws + 8L * MTOT * 4 + 64 * 512 * 4 + 512 * 1024 + 8192); // 128MB

    hipMemsetAsync(meta, 0, 8, stream);
    prep_wt_kernel<<<256, 256, 0, stream>>>(W1, Wt);
    prep_qc_kernel<<<64, 256, 0, stream>>>(query, W1, b1, qc);
    build_wl_kernel<<<4, 256, 0, stream>>>(length, wl, meta);
    prep_enc_kernel<<<1024, 256, 0, stream>>>(enc, length, Ab);

    gemm_logits_kernel<<<256, 512, 0, stream>>>(Ab, Wt, qc, v, wl, meta, part);

    softmax_kernel<<<64, 256, 0, stream>>>(part, length, att, ctx);

    dim3 g3(64, 16);
    ctx_kernel<<<g3, 256, 0, stream>>>(att, Ab, length, ctx);
}